// Round 1
// 197.304 us; speedup vs baseline: 1.0036x; 1.0036x over previous
//
#include <hip/hip_runtime.h>
#include <math.h>

#define Bq 8
#define Tq 4096
#define Dq 512
#define Hq 512
#define Mq (Bq * Tq)   // 32768
#define NC 64          // chunks along T
#define CL 64          // chunk length

typedef unsigned short ushort_t;
typedef unsigned int uint_t;
typedef __bf16 bf16x8 __attribute__((ext_vector_type(8)));
typedef float f32x4 __attribute__((ext_vector_type(4)));

__device__ __forceinline__ ushort_t f2bf(float f) {
    unsigned int u = __float_as_uint(f);
    unsigned int r = u + 0x7fffu + ((u >> 16) & 1u);
    return (ushort_t)(r >> 16);
}

// async global -> LDS, 16 bytes/lane; lds dest is wave-uniform base (+lane*16 by HW)
__device__ __forceinline__ void gload16(const void* g, void* l) {
    __builtin_amdgcn_global_load_lds(
        (const __attribute__((address_space(1))) void*)g,
        (__attribute__((address_space(3))) void*)l, 16, 0, 0);
}

// word = bf16(k) | bf16(th)<<16 -> c = 1-sigmoid(k), v = sigmoid(k)*g(th)
__device__ __forceinline__ void gates(uint_t w, float& c, float& v) {
    float k  = __uint_as_float((w & 0xffffu) << 16);
    float th = __uint_as_float(w & 0xffff0000u);
    float ek = __expf(k);
    c = 1.0f / (1.0f + ek);        // 1 - sigmoid(k)
    float z = 1.0f - c;            // sigmoid(k)
    float g = (th >= 0.0f) ? (th + 0.5f) : (1.0f / (1.0f + __expf(-th)));
    v = z * g;
}

// ---------------- convert x, Wz, Wh to bf16 (single pass) ----------------
__global__ __launch_bounds__(256)
void convert_all(const float* __restrict__ x, const float* __restrict__ Wz,
                 const float* __restrict__ Wh, ushort_t* __restrict__ dst) {
    size_t i8 = ((size_t)blockIdx.x * 256 + threadIdx.x) * 8;
    const size_t XN = (size_t)Mq * Dq;
    const size_t WN = (size_t)Hq * Dq;
    const float* src; size_t off;
    if (i8 < XN)            { src = x;  off = i8; }
    else if (i8 < XN + WN)  { src = Wz; off = i8 - XN; }
    else                    { src = Wh; off = i8 - XN - WN; }
    float4 a = *reinterpret_cast<const float4*>(src + off);
    float4 b = *reinterpret_cast<const float4*>(src + off + 4);
    uint4 o;
    o.x = (uint_t)f2bf(a.x) | ((uint_t)f2bf(a.y) << 16);
    o.y = (uint_t)f2bf(a.z) | ((uint_t)f2bf(a.w) << 16);
    o.z = (uint_t)f2bf(b.x) | ((uint_t)f2bf(b.y) << 16);
    o.w = (uint_t)f2bf(b.z) | ((uint_t)f2bf(b.w) << 16);
    *reinterpret_cast<uint4*>(dst + i8) = o;
}

// ---------------- fused dual GEMM + gates + per-chunk scan partials ----------------
__global__ __launch_bounds__(256, 2)
void gemm_fused(const ushort_t* __restrict__ xb, const ushort_t* __restrict__ wb,
                const float* __restrict__ bz, const float* __restrict__ bh,
                uint_t* __restrict__ kvout, float2* __restrict__ chAW) {
    __shared__ __align__(16) ushort_t smem[3 * 128 * 64];   // 48 KB
    ushort_t* As  = smem;
    ushort_t* Bzs = smem + 128 * 64;
    ushort_t* Bhs = smem + 2 * 128 * 64;

    const int tid  = threadIdx.x;
    const int lane = tid & 63;
    const int wave = tid >> 6;
    const int wm = (wave >> 1) * 64;
    const int wn = (wave & 1) * 64;
    const int mBase = blockIdx.x * 128;
    const int nBase = blockIdx.y * 128;
    const ushort_t* Wzb = wb;
    const ushort_t* Whb = wb + (size_t)Hq * Dq;

    f32x4 zero = {0.f, 0.f, 0.f, 0.f};
    f32x4 accz[4][4], acch[4][4];
#pragma unroll
    for (int i = 0; i < 4; ++i)
#pragma unroll
        for (int j = 0; j < 4; ++j) { accz[i][j] = zero; acch[i][j] = zero; }

    const int rowInW = lane >> 3;
    const int ccG = (lane & 7) ^ rowInW;   // xor-swizzled global chunk
    const int swz = lane & 7;              // read-side swizzle

    for (int k0 = 0; k0 < Dq; k0 += 64) {
#pragma unroll
        for (int j = 0; j < 4; ++j) {
            const int rseg = j * 4 + wave;
            const int row  = rseg * 8 + rowInW;
            const size_t gcol = (size_t)(k0 + ccG * 8);
            gload16(xb  + (size_t)(mBase + row) * Dq + gcol, &As [rseg * 512]);
            gload16(Wzb + (size_t)(nBase + row) * Dq + gcol, &Bzs[rseg * 512]);
            gload16(Whb + (size_t)(nBase + row) * Dq + gcol, &Bhs[rseg * 512]);
        }
        __syncthreads();

#pragma unroll
        for (int ks = 0; ks < 2; ++ks) {
            const int cc = ks * 4 + (lane >> 4);
            const int sc = cc ^ swz;
            bf16x8 af[4], bzf[4], bhf[4];
#pragma unroll
            for (int i = 0; i < 4; ++i) {
                int rowA = wm + i * 16 + (lane & 15);
                af[i] = *reinterpret_cast<const bf16x8*>(&As[rowA * 64 + sc * 8]);
            }
#pragma unroll
            for (int i = 0; i < 4; ++i) {
                int rowB = wn + i * 16 + (lane & 15);
                bzf[i] = *reinterpret_cast<const bf16x8*>(&Bzs[rowB * 64 + sc * 8]);
                bhf[i] = *reinterpret_cast<const bf16x8*>(&Bhs[rowB * 64 + sc * 8]);
            }
#pragma unroll
            for (int mi = 0; mi < 4; ++mi)
#pragma unroll
                for (int ni = 0; ni < 4; ++ni) {
                    accz[mi][ni] = __builtin_amdgcn_mfma_f32_16x16x32_bf16(
                        af[mi], bzf[ni], accz[mi][ni], 0, 0, 0);
                    acch[mi][ni] = __builtin_amdgcn_mfma_f32_16x16x32_bf16(
                        af[mi], bhf[ni], acch[mi][ni], 0, 0, 0);
                }
        }
        __syncthreads();
    }

    // ---- epilogue: write packed kv AND per-chunk affine partials ----
    // C/D layout: col = lane&15, row = (lane>>4)*4 + r. Wave quadrant covers
    // exactly one T-chunk (rows wm..wm+63 of a 128-row tile; 64 == CL).
    const int colL = lane & 15;
    const int quad = lane >> 4;
    float2* sb = reinterpret_cast<float2*>(smem) + wave * 1024;  // [16 seg][64 col]

#pragma unroll
    for (int ni = 0; ni < 4; ++ni) {
        int h = nBase + wn + ni * 16 + colL;
        float bzv = bz[h];
        float bhv = bh[h];
#pragma unroll
        for (int mi = 0; mi < 4; ++mi) {
            float A = 1.f, W = 0.f;
#pragma unroll
            for (int r = 0; r < 4; ++r) {
                int bt = mBase + wm + mi * 16 + quad * 4 + r;
                float kf  = accz[mi][ni][r] + bzv;
                float thf = acch[mi][ni][r] + bhv;
                uint_t word = (uint_t)f2bf(kf) | ((uint_t)f2bf(thf) << 16);
                kvout[(size_t)bt * Hq + h] = word;
                float c, v;
                gates(word, c, v);           // from ROUNDED values: matches replay
                W = fmaf(c, W, v);
                A *= c;
            }
            sb[(mi * 4 + quad) * 64 + ni * 16 + colL] = make_float2(A, W);
        }
    }
    __syncthreads();
    {
        float A = 1.f, W = 0.f;
#pragma unroll
        for (int s = 0; s < 16; ++s) {       // seg = mi*4 + quad: increasing t
            float2 aw = sb[s * 64 + lane];
            W = fmaf(aw.x, W, aw.y);
            A *= aw.x;
        }
        int g = blockIdx.x * 2 + (wm >> 6);  // global chunk id = b*NC + chunk
        int h = nBase + wn + lane;
        chAW[(size_t)g * Hq + h] = make_float2(A, W);
    }
}

// ---------------- fused combine + replay: one h per thread ----------------
// Each block = one (b, chunk). Prefix over chunks < c computed in-block from
// chAW (2 MB, L2/L3-resident) -- identical arithmetic/order to the old
// scan_combine, so numerics are unchanged. kv aliases out; each address is
// read (batched, earlier t-rows) before the SAME thread writes it.
__global__ __launch_bounds__(512)
void scan_final(const uint_t* kv, const float* __restrict__ h0,
                const float2* __restrict__ chAW, float* out) {
    const int b = blockIdx.x & 7;
    const int chunk = 63 - (blockIdx.x >> 3);  // heavy-prefix blocks launch first
    const int h = threadIdx.x;                  // 0..511

    float x0 = h0[(size_t)b * Hq + h];
    float r = (x0 >= 0.f) ? (x0 + 0.5f) : (1.f / (1.f + __expf(-x0)));

    // ---- prefix over chunks 0..chunk-1 (uniform trip count per block) ----
    const float2* p = chAW + (size_t)b * NC * Hq + h;
    int j = 0;
    for (; j + 8 <= chunk; j += 8) {
        float2 aw[8];
#pragma unroll
        for (int q = 0; q < 8; ++q) aw[q] = p[(size_t)(j + q) * Hq];
#pragma unroll
        for (int q = 0; q < 8; ++q) r = fmaf(aw[q].x, r, aw[q].y);
    }
    for (; j < chunk; ++j) {
        float2 aw = p[(size_t)j * Hq];
        r = fmaf(aw.x, r, aw.y);
    }

    // ---- replay 64 steps with true prefix, batch-16 double-buffered ----
    const size_t base = ((size_t)b * Tq + (size_t)chunk * CL) * Hq + h;
    const uint_t* kvp = kv + base;
    float* op = out + base;

    uint_t w[16];
#pragma unroll
    for (int q = 0; q < 16; ++q) w[q] = kvp[(size_t)q * Hq];
    for (int bt = 0; bt < 4; ++bt) {
        uint_t wn[16];
        if (bt < 3) {
#pragma unroll
            for (int q = 0; q < 16; ++q)
                wn[q] = kvp[(size_t)((bt + 1) * 16 + q) * Hq];
        }
#pragma unroll
        for (int q = 0; q < 16; ++q) {
            float c, v;
            gates(w[q], c, v);
            r = fmaf(c, r, v);
            op[(size_t)(bt * 16 + q) * Hq] = r;
        }
#pragma unroll
        for (int q = 0; q < 16; ++q) w[q] = wn[q];
    }
}

extern "C" void kernel_launch(void* const* d_in, const int* in_sizes, int n_in,
                              void* d_out, int out_size, void* d_ws, size_t ws_size,
                              hipStream_t stream) {
    const float* x  = (const float*)d_in[0];
    const float* h0 = (const float*)d_in[1];
    const float* Wz = (const float*)d_in[2];
    const float* bz = (const float*)d_in[3];
    const float* Wh = (const float*)d_in[4];
    const float* bh = (const float*)d_in[5];
    float* out = (float*)d_out;

    // ws layout (~35 MB): xb 32MB | wb 1MB | chAW 2MB
    char* ws = (char*)d_ws;
    ushort_t* xb = (ushort_t*)ws;
    ushort_t* wb = xb + (size_t)Mq * Dq;
    float2* chAW = (float2*)(wb + 2 * (size_t)Hq * Dq);
    uint_t* kv = (uint_t*)d_out;

    const int totalConv = (Mq * Dq + 2 * Hq * Dq) / (256 * 8);
    convert_all<<<dim3(totalConv), dim3(256), 0, stream>>>(x, Wz, Wh, xb);
    gemm_fused<<<dim3(Mq / 128, Hq / 128), dim3(256), 0, stream>>>(xb, wb, bz, bh, kv, chAW);
    scan_final<<<dim3(Bq * NC), dim3(512), 0, stream>>>(kv, h0, chAW, out);
}

// Round 2
// 196.018 us; speedup vs baseline: 1.0102x; 1.0066x over previous
//
#include <hip/hip_runtime.h>
#include <math.h>

#define Bq 8
#define Tq 4096
#define Dq 512
#define Hq 512
#define Mq (Bq * Tq)   // 32768
#define NC 64          // chunks along T
#define CL 64          // chunk length
#define BK 32          // K-tile (bf16 elems)
#define NKT (Dq / BK)  // 16 K-tiles

typedef unsigned short ushort_t;
typedef unsigned int uint_t;
typedef __bf16 bf16x8 __attribute__((ext_vector_type(8)));
typedef float f32x4 __attribute__((ext_vector_type(4)));

__device__ __forceinline__ ushort_t f2bf(float f) {
    unsigned int u = __float_as_uint(f);
    unsigned int r = u + 0x7fffu + ((u >> 16) & 1u);
    return (ushort_t)(r >> 16);
}

// async global -> LDS, 16 bytes/lane; lds dest is wave-uniform base (+lane*16 by HW)
__device__ __forceinline__ void gload16(const void* g, void* l) {
    __builtin_amdgcn_global_load_lds(
        (const __attribute__((address_space(1))) void*)g,
        (__attribute__((address_space(3))) void*)l, 16, 0, 0);
}

// word = bf16(k) | bf16(th)<<16 -> c = 1-sigmoid(k), v = sigmoid(k)*g(th)
__device__ __forceinline__ void gates(uint_t w, float& c, float& v) {
    float k  = __uint_as_float((w & 0xffffu) << 16);
    float th = __uint_as_float(w & 0xffff0000u);
    float ek = __expf(k);
    c = 1.0f / (1.0f + ek);        // 1 - sigmoid(k)
    float z = 1.0f - c;            // sigmoid(k)
    float g = (th >= 0.0f) ? (th + 0.5f) : (1.0f / (1.0f + __expf(-th)));
    v = z * g;
}

// ---------------- convert x, Wz, Wh to bf16 (single pass) ----------------
__global__ __launch_bounds__(256)
void convert_all(const float* __restrict__ x, const float* __restrict__ Wz,
                 const float* __restrict__ Wh, ushort_t* __restrict__ dst) {
    size_t i8 = ((size_t)blockIdx.x * 256 + threadIdx.x) * 8;
    const size_t XN = (size_t)Mq * Dq;
    const size_t WN = (size_t)Hq * Dq;
    const float* src; size_t off;
    if (i8 < XN)            { src = x;  off = i8; }
    else if (i8 < XN + WN)  { src = Wz; off = i8 - XN; }
    else                    { src = Wh; off = i8 - XN - WN; }
    float4 a = *reinterpret_cast<const float4*>(src + off);
    float4 b = *reinterpret_cast<const float4*>(src + off + 4);
    uint4 o;
    o.x = (uint_t)f2bf(a.x) | ((uint_t)f2bf(a.y) << 16);
    o.y = (uint_t)f2bf(a.z) | ((uint_t)f2bf(a.w) << 16);
    o.z = (uint_t)f2bf(b.x) | ((uint_t)f2bf(b.y) << 16);
    o.w = (uint_t)f2bf(b.z) | ((uint_t)f2bf(b.w) << 16);
    *reinterpret_cast<uint4*>(dst + i8) = o;
}

// ---------------- fused dual GEMM + gates + per-chunk scan partials ----------------
// T3-minimum pipeline: BK=32, triple-buffered LDS, 2-tiles-ahead prefetch with
// counted vmcnt (never drains to 0 in steady state) + raw s_barrier.
__global__ __launch_bounds__(256, 2)
void gemm_fused(const ushort_t* __restrict__ xb, const ushort_t* __restrict__ wb,
                const float* __restrict__ bz, const float* __restrict__ bh,
                uint_t* __restrict__ kvout, float2* __restrict__ chAW) {
    // per buf: {A[128][32], Bz[128][32], Bh[128][32]} bf16 = 24 KB; 3 bufs = 72 KB
    __shared__ __align__(16) ushort_t smem[3 * 3 * 128 * BK];

    const int tid  = threadIdx.x;
    const int lane = tid & 63;
    const int wave = tid >> 6;
    const int wm = (wave >> 1) * 64;
    const int wn = (wave & 1) * 64;
    const int mBase = blockIdx.x * 128;
    const int nBase = blockIdx.y * 128;
    const ushort_t* Wzb = wb;
    const ushort_t* Whb = wb + (size_t)Hq * Dq;

    f32x4 zero = {0.f, 0.f, 0.f, 0.f};
    f32x4 accz[4][4], acch[4][4];
#pragma unroll
    for (int i = 0; i < 4; ++i)
#pragma unroll
        for (int j = 0; j < 4; ++j) { accz[i][j] = zero; acch[i][j] = zero; }

    // staging geometry: each wave stages rows [wave*32, wave*32+32) in 2 rounds
    // of 16 rows (1 KB linear LDS per round). Physical chunk pc = lane&3 holds
    // logical chunk lc = pc ^ ((row>>1)&3)  (inverse-swizzled global source).
    const int srowL = lane >> 2;   // row within round
    const int spc   = lane & 3;    // physical 16B chunk

    ushort_t* const b0 = smem;
    ushort_t* const b1 = smem + 3 * 128 * BK;
    ushort_t* const b2 = smem + 6 * 128 * BK;
    ushort_t* bufs[3] = {b0, b1, b2};

    auto STAGE = [&](int t, ushort_t* buf) {
        const int k0 = t * BK;
#pragma unroll
        for (int j = 0; j < 2; ++j) {
            const int r   = wave * 2 + j;               // round 0..7
            const int row = r * 16 + srowL;             // 0..127
            const int lc  = spc ^ ((row >> 1) & 3);
            const size_t gcol = (size_t)(k0 + lc * 8);
            ushort_t* ldst = buf + r * 512;             // wave-uniform base
            gload16(xb  + (size_t)(mBase + row) * Dq + gcol, ldst);
            gload16(Wzb + (size_t)(nBase + row) * Dq + gcol, ldst + 128 * BK);
            gload16(Whb + (size_t)(nBase + row) * Dq + gcol, ldst + 2 * 128 * BK);
        }
    };

    STAGE(0, b0);
    STAGE(1, b1);
    asm volatile("s_waitcnt vmcnt(6)" ::: "memory");   // tile 0 landed; tile 1 in flight
    __builtin_amdgcn_s_barrier();

    const int rl15 = lane & 15;
    const int cc   = lane >> 4;    // k-chunk this lane feeds the MFMA

#pragma unroll
    for (int t = 0; t < NKT; ++t) {
        const ushort_t* A   = bufs[t % 3];
        const ushort_t* Bzs = A + 128 * BK;
        const ushort_t* Bhs = A + 2 * 128 * BK;
        bf16x8 af[4], bzf[4], bhf[4];
#pragma unroll
        for (int i = 0; i < 4; ++i) {
            const int rowA = wm + i * 16 + rl15;
            const int pA   = cc ^ ((rowA >> 1) & 3);
            af[i] = *reinterpret_cast<const bf16x8*>(A + rowA * BK + pA * 8);
            const int rowB = wn + i * 16 + rl15;
            const int pB   = cc ^ ((rowB >> 1) & 3);
            bzf[i] = *reinterpret_cast<const bf16x8*>(Bzs + rowB * BK + pB * 8);
            bhf[i] = *reinterpret_cast<const bf16x8*>(Bhs + rowB * BK + pB * 8);
        }
        if (t + 2 < NKT) STAGE(t + 2, bufs[(t + 2) % 3]);  // overwrites buf(t-1): safe,
                                                           // all waves' t-1 ds_reads done
#pragma unroll
        for (int mi = 0; mi < 4; ++mi)
#pragma unroll
            for (int ni = 0; ni < 4; ++ni) {
                accz[mi][ni] = __builtin_amdgcn_mfma_f32_16x16x32_bf16(
                    af[mi], bzf[ni], accz[mi][ni], 0, 0, 0);
                acch[mi][ni] = __builtin_amdgcn_mfma_f32_16x16x32_bf16(
                    af[mi], bhf[ni], acch[mi][ni], 0, 0, 0);
            }
        if (t < NKT - 2) {
            // counted: leaves tile t+2's 6 loads in flight, guarantees t+1 ready
            asm volatile("s_waitcnt vmcnt(6)" ::: "memory");
            __builtin_amdgcn_s_barrier();
        } else if (t < NKT - 1) {
            asm volatile("s_waitcnt vmcnt(0)" ::: "memory");
            __builtin_amdgcn_s_barrier();
        }
    }
    __builtin_amdgcn_s_barrier();   // protect smem reuse (sb aliases buf0/buf1)

    // ---- epilogue: write packed kv AND per-chunk affine partials ----
    // C/D layout: col = lane&15, row = (lane>>4)*4 + r. Wave quadrant covers
    // exactly one T-chunk (rows wm..wm+63 of a 128-row tile; 64 == CL).
    const int colL = lane & 15;
    const int quad = lane >> 4;
    float2* sb = reinterpret_cast<float2*>(smem) + wave * 1024;  // [16 seg][64 col]

#pragma unroll
    for (int ni = 0; ni < 4; ++ni) {
        int h = nBase + wn + ni * 16 + colL;
        float bzv = bz[h];
        float bhv = bh[h];
#pragma unroll
        for (int mi = 0; mi < 4; ++mi) {
            float A = 1.f, W = 0.f;
#pragma unroll
            for (int r = 0; r < 4; ++r) {
                int bt = mBase + wm + mi * 16 + quad * 4 + r;
                float kf  = accz[mi][ni][r] + bzv;
                float thf = acch[mi][ni][r] + bhv;
                uint_t word = (uint_t)f2bf(kf) | ((uint_t)f2bf(thf) << 16);
                kvout[(size_t)bt * Hq + h] = word;
                float c, v;
                gates(word, c, v);           // from ROUNDED values: matches replay
                W = fmaf(c, W, v);
                A *= c;
            }
            sb[(mi * 4 + quad) * 64 + ni * 16 + colL] = make_float2(A, W);
        }
    }
    __syncthreads();
    {
        float A = 1.f, W = 0.f;
#pragma unroll
        for (int s = 0; s < 16; ++s) {       // seg = mi*4 + quad: increasing t
            float2 aw = sb[s * 64 + lane];
            W = fmaf(aw.x, W, aw.y);
            A *= aw.x;
        }
        int g = blockIdx.x * 2 + (wm >> 6);  // global chunk id = b*NC + chunk
        int h = nBase + wn + lane;
        chAW[(size_t)g * Hq + h] = make_float2(A, W);
    }
}

// ---------------- fused combine + replay: one h per thread ----------------
__global__ __launch_bounds__(512)
void scan_final(const uint_t* kv, const float* __restrict__ h0,
                const float2* __restrict__ chAW, float* out) {
    const int b = blockIdx.x & 7;
    const int chunk = 63 - (blockIdx.x >> 3);  // heavy-prefix blocks launch first
    const int h = threadIdx.x;                  // 0..511

    float x0 = h0[(size_t)b * Hq + h];
    float r = (x0 >= 0.f) ? (x0 + 0.5f) : (1.f / (1.f + __expf(-x0)));

    // ---- prefix over chunks 0..chunk-1 ----
    const float2* p = chAW + (size_t)b * NC * Hq + h;
    int j = 0;
    for (; j + 8 <= chunk; j += 8) {
        float2 aw[8];
#pragma unroll
        for (int q = 0; q < 8; ++q) aw[q] = p[(size_t)(j + q) * Hq];
#pragma unroll
        for (int q = 0; q < 8; ++q) r = fmaf(aw[q].x, r, aw[q].y);
    }
    for (; j < chunk; ++j) {
        float2 aw = p[(size_t)j * Hq];
        r = fmaf(aw.x, r, aw.y);
    }

    // ---- replay 64 steps with true prefix, batch-16 double-buffered ----
    const size_t base = ((size_t)b * Tq + (size_t)chunk * CL) * Hq + h;
    const uint_t* kvp = kv + base;
    float* op = out + base;

    uint_t w[16];
#pragma unroll
    for (int q = 0; q < 16; ++q) w[q] = kvp[(size_t)q * Hq];
    for (int bt = 0; bt < 4; ++bt) {
        uint_t wn[16];
        if (bt < 3) {
#pragma unroll
            for (int q = 0; q < 16; ++q)
                wn[q] = kvp[(size_t)((bt + 1) * 16 + q) * Hq];
        }
#pragma unroll
        for (int q = 0; q < 16; ++q) {
            float c, v;
            gates(w[q], c, v);
            r = fmaf(c, r, v);
            op[(size_t)(bt * 16 + q) * Hq] = r;
        }
#pragma unroll
        for (int q = 0; q < 16; ++q) w[q] = wn[q];
    }
}

extern "C" void kernel_launch(void* const* d_in, const int* in_sizes, int n_in,
                              void* d_out, int out_size, void* d_ws, size_t ws_size,
                              hipStream_t stream) {
    const float* x  = (const float*)d_in[0];
    const float* h0 = (const float*)d_in[1];
    const float* Wz = (const float*)d_in[2];
    const float* bz = (const float*)d_in[3];
    const float* Wh = (const float*)d_in[4];
    const float* bh = (const float*)d_in[5];
    float* out = (float*)d_out;

    // ws layout (~35 MB): xb 32MB | wb 1MB | chAW 2MB
    char* ws = (char*)d_ws;
    ushort_t* xb = (ushort_t*)ws;
    ushort_t* wb = xb + (size_t)Mq * Dq;
    float2* chAW = (float2*)(wb + 2 * (size_t)Hq * Dq);
    uint_t* kv = (uint_t*)d_out;

    const int totalConv = (Mq * Dq + 2 * Hq * Dq) / (256 * 8);
    convert_all<<<dim3(totalConv), dim3(256), 0, stream>>>(x, Wz, Wh, xb);
    gemm_fused<<<dim3(Mq / 128, Hq / 128), dim3(256), 0, stream>>>(xb, wb, bz, bh, kv, chAW);
    scan_final<<<dim3(Bq * NC), dim3(512), 0, stream>>>(kv, h0, chAW, out);
}

// Round 3
// 195.102 us; speedup vs baseline: 1.0149x; 1.0047x over previous
//
#include <hip/hip_runtime.h>
#include <math.h>

#define Bq 8
#define Tq 4096
#define Dq 512
#define Hq 512
#define Mq (Bq * Tq)   // 32768
#define NC 64          // chunks along T
#define CL 64          // chunk length

typedef unsigned short ushort_t;
typedef unsigned int uint_t;
typedef __bf16 bf16x8 __attribute__((ext_vector_type(8)));
typedef float f32x4 __attribute__((ext_vector_type(4)));

__device__ __forceinline__ ushort_t f2bf(float f) {
    unsigned int u = __float_as_uint(f);
    unsigned int r = u + 0x7fffu + ((u >> 16) & 1u);
    return (ushort_t)(r >> 16);
}

// async global -> LDS, 16 bytes/lane; lds dest is wave-uniform base (+lane*16 by HW)
__device__ __forceinline__ void gload16(const void* g, void* l) {
    __builtin_amdgcn_global_load_lds(
        (const __attribute__((address_space(1))) void*)g,
        (__attribute__((address_space(3))) void*)l, 16, 0, 0);
}

// word = bf16(k) | bf16(th)<<16 -> c = 1-sigmoid(k), v = sigmoid(k)*g(th)
__device__ __forceinline__ void gates(uint_t w, float& c, float& v) {
    float k  = __uint_as_float((w & 0xffffu) << 16);
    float th = __uint_as_float(w & 0xffff0000u);
    float ek = __expf(k);
    c = 1.0f / (1.0f + ek);        // 1 - sigmoid(k)
    float z = 1.0f - c;            // sigmoid(k)
    float g = (th >= 0.0f) ? (th + 0.5f) : (1.0f / (1.0f + __expf(-th)));
    v = z * g;
}

// ---------------- convert Wz, Wh to bf16 (tiny: 2 MB in, 1 MB out) ----------------
__global__ __launch_bounds__(256)
void convert_w(const float* __restrict__ Wz, const float* __restrict__ Wh,
               ushort_t* __restrict__ dst) {
    size_t i8 = ((size_t)blockIdx.x * 256 + threadIdx.x) * 8;
    const size_t WN = (size_t)Hq * Dq;
    const float* src = (i8 < WN) ? Wz : Wh;
    size_t off = (i8 < WN) ? i8 : i8 - WN;
    float4 a = *reinterpret_cast<const float4*>(src + off);
    float4 b = *reinterpret_cast<const float4*>(src + off + 4);
    uint4 o;
    o.x = (uint_t)f2bf(a.x) | ((uint_t)f2bf(a.y) << 16);
    o.y = (uint_t)f2bf(a.z) | ((uint_t)f2bf(a.w) << 16);
    o.z = (uint_t)f2bf(b.x) | ((uint_t)f2bf(b.y) << 16);
    o.w = (uint_t)f2bf(b.z) | ((uint_t)f2bf(b.w) << 16);
    *reinterpret_cast<uint4*>(dst + i8) = o;
}

// ---------------- fused convert(x) + dual GEMM + gates + chunk partials ----------
// A-path: reg-staged f32 x -> f2bf -> swizzled ds_write (bit-identical LDS bytes
// to the old gload16-of-xb path). B-path: async gload16 of pre-converted weights.
__global__ __launch_bounds__(256, 2)
void gemm_fused(const float* __restrict__ x, const ushort_t* __restrict__ wb,
                const float* __restrict__ bz, const float* __restrict__ bh,
                uint_t* __restrict__ kvout, float2* __restrict__ chAW) {
    __shared__ __align__(16) ushort_t smem[3 * 128 * 64];   // 48 KB
    ushort_t* As  = smem;
    ushort_t* Bzs = smem + 128 * 64;
    ushort_t* Bhs = smem + 2 * 128 * 64;

    const int tid  = threadIdx.x;
    const int lane = tid & 63;
    const int wave = tid >> 6;
    const int wm = (wave >> 1) * 64;
    const int wn = (wave & 1) * 64;
    const int mBase = blockIdx.x * 128;
    const int nBase = blockIdx.y * 128;
    const ushort_t* Wzb = wb;
    const ushort_t* Whb = wb + (size_t)Hq * Dq;

    f32x4 zero = {0.f, 0.f, 0.f, 0.f};
    f32x4 accz[4][4], acch[4][4];
#pragma unroll
    for (int i = 0; i < 4; ++i)
#pragma unroll
        for (int j = 0; j < 4; ++j) { accz[i][j] = zero; acch[i][j] = zero; }

    // staging geometry (same swizzle as before): lane L covers row (L>>3) of an
    // 8-row segment, physical 16B chunk p = L&7 holding logical chunk lc = p^(L>>3).
    const int rowInW = lane >> 3;
    const int ccG = (lane & 7) ^ rowInW;   // logical chunk staged by this lane
    const int swz = lane & 7;              // read-side swizzle

    for (int k0 = 0; k0 < Dq; k0 += 64) {
#pragma unroll
        for (int j = 0; j < 4; ++j) {
            const int rseg = j * 4 + wave;
            const int row  = rseg * 8 + rowInW;
            const size_t gcol = (size_t)(k0 + ccG * 8);
            // A: f32 load + convert + swizzled LDS write (same bytes as before)
            const float* xs = x + (size_t)(mBase + row) * Dq + gcol;
            float4 a = *reinterpret_cast<const float4*>(xs);
            float4 b = *reinterpret_cast<const float4*>(xs + 4);
            uint4 o;
            o.x = (uint_t)f2bf(a.x) | ((uint_t)f2bf(a.y) << 16);
            o.y = (uint_t)f2bf(a.z) | ((uint_t)f2bf(a.w) << 16);
            o.z = (uint_t)f2bf(b.x) | ((uint_t)f2bf(b.y) << 16);
            o.w = (uint_t)f2bf(b.z) | ((uint_t)f2bf(b.w) << 16);
            *reinterpret_cast<uint4*>(As + rseg * 512 + lane * 8) = o;
            // B: async direct-to-LDS (dest wave-uniform base + lane*16 by HW)
            gload16(Wzb + (size_t)(nBase + row) * Dq + gcol, &Bzs[rseg * 512]);
            gload16(Whb + (size_t)(nBase + row) * Dq + gcol, &Bhs[rseg * 512]);
        }
        __syncthreads();

#pragma unroll
        for (int ks = 0; ks < 2; ++ks) {
            const int cc = ks * 4 + (lane >> 4);
            const int sc = cc ^ swz;
            bf16x8 af[4], bzf[4], bhf[4];
#pragma unroll
            for (int i = 0; i < 4; ++i) {
                int rowA = wm + i * 16 + (lane & 15);
                af[i] = *reinterpret_cast<const bf16x8*>(&As[rowA * 64 + sc * 8]);
            }
#pragma unroll
            for (int i = 0; i < 4; ++i) {
                int rowB = wn + i * 16 + (lane & 15);
                bzf[i] = *reinterpret_cast<const bf16x8*>(&Bzs[rowB * 64 + sc * 8]);
                bhf[i] = *reinterpret_cast<const bf16x8*>(&Bhs[rowB * 64 + sc * 8]);
            }
#pragma unroll
            for (int mi = 0; mi < 4; ++mi)
#pragma unroll
                for (int ni = 0; ni < 4; ++ni) {
                    accz[mi][ni] = __builtin_amdgcn_mfma_f32_16x16x32_bf16(
                        af[mi], bzf[ni], accz[mi][ni], 0, 0, 0);
                    acch[mi][ni] = __builtin_amdgcn_mfma_f32_16x16x32_bf16(
                        af[mi], bhf[ni], acch[mi][ni], 0, 0, 0);
                }
        }
        __syncthreads();
    }

    // ---- epilogue: write packed kv AND per-chunk affine partials ----
    // C/D layout: col = lane&15, row = (lane>>4)*4 + r. Wave quadrant covers
    // exactly one T-chunk (rows wm..wm+63 of a 128-row tile; 64 == CL).
    const int colL = lane & 15;
    const int quad = lane >> 4;
    float2* sb = reinterpret_cast<float2*>(smem) + wave * 1024;  // [16 seg][64 col]

#pragma unroll
    for (int ni = 0; ni < 4; ++ni) {
        int h = nBase + wn + ni * 16 + colL;
        float bzv = bz[h];
        float bhv = bh[h];
#pragma unroll
        for (int mi = 0; mi < 4; ++mi) {
            float A = 1.f, W = 0.f;
#pragma unroll
            for (int r = 0; r < 4; ++r) {
                int bt = mBase + wm + mi * 16 + quad * 4 + r;
                float kf  = accz[mi][ni][r] + bzv;
                float thf = acch[mi][ni][r] + bhv;
                uint_t word = (uint_t)f2bf(kf) | ((uint_t)f2bf(thf) << 16);
                kvout[(size_t)bt * Hq + h] = word;
                float c, v;
                gates(word, c, v);           // from ROUNDED values: matches replay
                W = fmaf(c, W, v);
                A *= c;
            }
            sb[(mi * 4 + quad) * 64 + ni * 16 + colL] = make_float2(A, W);
        }
    }
    __syncthreads();
    {
        float A = 1.f, W = 0.f;
#pragma unroll
        for (int s = 0; s < 16; ++s) {       // seg = mi*4 + quad: increasing t
            float2 aw = sb[s * 64 + lane];
            W = fmaf(aw.x, W, aw.y);
            A *= aw.x;
        }
        int g = blockIdx.x * 2 + (wm >> 6);  // global chunk id = b*NC + chunk
        int h = nBase + wn + lane;
        chAW[(size_t)g * Hq + h] = make_float2(A, W);
    }
}

// ---------------- fused combine + replay: one h per thread ----------------
__global__ __launch_bounds__(512)
void scan_final(const uint_t* kv, const float* __restrict__ h0,
                const float2* __restrict__ chAW, float* out) {
    const int b = blockIdx.x & 7;
    const int chunk = 63 - (blockIdx.x >> 3);  // heavy-prefix blocks launch first
    const int h = threadIdx.x;                  // 0..511

    float x0 = h0[(size_t)b * Hq + h];
    float r = (x0 >= 0.f) ? (x0 + 0.5f) : (1.f / (1.f + __expf(-x0)));

    // ---- prefix over chunks 0..chunk-1 ----
    const float2* p = chAW + (size_t)b * NC * Hq + h;
    int j = 0;
    for (; j + 8 <= chunk; j += 8) {
        float2 aw[8];
#pragma unroll
        for (int q = 0; q < 8; ++q) aw[q] = p[(size_t)(j + q) * Hq];
#pragma unroll
        for (int q = 0; q < 8; ++q) r = fmaf(aw[q].x, r, aw[q].y);
    }
    for (; j < chunk; ++j) {
        float2 aw = p[(size_t)j * Hq];
        r = fmaf(aw.x, r, aw.y);
    }

    // ---- replay 64 steps with true prefix, batch-16 double-buffered ----
    const size_t base = ((size_t)b * Tq + (size_t)chunk * CL) * Hq + h;
    const uint_t* kvp = kv + base;
    float* op = out + base;

    uint_t w[16];
#pragma unroll
    for (int q = 0; q < 16; ++q) w[q] = kvp[(size_t)q * Hq];
    for (int bt = 0; bt < 4; ++bt) {
        uint_t wn[16];
        if (bt < 3) {
#pragma unroll
            for (int q = 0; q < 16; ++q)
                wn[q] = kvp[(size_t)((bt + 1) * 16 + q) * Hq];
        }
#pragma unroll
        for (int q = 0; q < 16; ++q) {
            float c, v;
            gates(w[q], c, v);
            r = fmaf(c, r, v);
            op[(size_t)(bt * 16 + q) * Hq] = r;
        }
#pragma unroll
        for (int q = 0; q < 16; ++q) w[q] = wn[q];
    }
}

extern "C" void kernel_launch(void* const* d_in, const int* in_sizes, int n_in,
                              void* d_out, int out_size, void* d_ws, size_t ws_size,
                              hipStream_t stream) {
    const float* x  = (const float*)d_in[0];
    const float* h0 = (const float*)d_in[1];
    const float* Wz = (const float*)d_in[2];
    const float* bz = (const float*)d_in[3];
    const float* Wh = (const float*)d_in[4];
    const float* bh = (const float*)d_in[5];
    float* out = (float*)d_out;

    // ws layout (~3 MB): wb 1MB | chAW 2MB
    char* ws = (char*)d_ws;
    ushort_t* wb = (ushort_t*)ws;
    float2* chAW = (float2*)(wb + 2 * (size_t)Hq * Dq);
    uint_t* kv = (uint_t*)d_out;

    const int wConv = (2 * Hq * Dq) / (256 * 8);
    convert_w<<<dim3(wConv), dim3(256), 0, stream>>>(Wz, Wh, wb);
    gemm_fused<<<dim3(Mq / 128, Hq / 128), dim3(256), 0, stream>>>(x, wb, bz, bh, kv, chAW);
    scan_final<<<dim3(Bq * NC), dim3(512), 0, stream>>>(kv, h0, chAW, out);
}